// Round 12
// baseline (385.358 us; speedup 1.0000x reference)
//
#include <hip/hip_runtime.h>

// Encoder: B=512, T=128, N=128, H=256
// Round 16: delete k_gemm<256,1> — Q fused into k_attn (attn main loop and
//   k_rnn structure otherwise untouched from R15's 336.9us config).
//   - k_attn prologue: stage Hb tile [32t][264] in LDS (unioned with qs ->
//     LDS still 33.9KB, 4 blocks/CU), 2 MFMA tiles/wave (8-deep chains in
//     gemm<256,1>'s exact k-order -> bit-identical Q), exp2 -> qs. Q never
//     touches HBM (saves 33.5MB write + 33.5MB read + a whole dispatch).
//   - xw in f16: gemm<128,0> writes hf (67->33.5MB), k_rnn loads hf4+cvt.
//   k_rnn: R15 16-wave operand-swapped recurrence (raw lgkm barrier, dist-2).
// Workspace (f32 offsets): P 0 | xw(hf) 8388608 | Hb(hf) 25165824 | wts(hf) 33554432

#define C2L 2.8853900817779268f   // 2*log2(e)
#define L2E 1.4426950408889634f   // log2(e)

typedef _Float16 hf;
typedef _Float16 hf4 __attribute__((ext_vector_type(4)));
typedef _Float16 hf8 __attribute__((ext_vector_type(8)));
typedef float f32x4 __attribute__((ext_vector_type(4)));

__device__ __forceinline__ float fast_exp2(float x){
#if __has_builtin(__builtin_amdgcn_exp2f)
  return __builtin_amdgcn_exp2f(x);
#else
  return exp2f(x);
#endif
}
__device__ __forceinline__ float fast_rcp(float x){
#if __has_builtin(__builtin_amdgcn_rcpf)
  return __builtin_amdgcn_rcpf(x);
#else
  return 1.f/x;
#endif
}
__device__ __forceinline__ float4 ld4h(const hf* p){
  hf4 h = *(const hf4*)p;
  return (float4){(float)h.x, (float)h.y, (float)h.z, (float)h.w};
}

// ---------------- weight prep: f32 [k][n] -> f16 [n][k] ----------------
__global__ __launch_bounds__(256) void k_prep_w(const float* __restrict__ Wx,
    const float* __restrict__ W2, const float* __restrict__ W1,
    hf* __restrict__ wts){
  int tid = blockIdx.x*256 + threadIdx.x;   // 320 blocks -> 81920 threads
  if (tid < 32768){                          // Wxt[n<256][k<128]
    int n = tid >> 7, k = tid & 127;
    wts[tid] = (hf)Wx[k*256 + n];
  } else if (tid < 65536){                   // W2t[n<128][k<256]
    int t2 = tid - 32768;
    int n = t2 >> 8, k = t2 & 255;
    wts[tid] = (hf)W2[k*128 + n];
  } else {                                   // W1t[n<128][k<128]
    int t3 = tid - 65536;
    int n = t3 >> 7, k = t3 & 127;
    wts[tid] = (hf)W1[k*128 + n];
  }
}

// ---------------- MFMA GEMM (MODE0: xw=data@Wx -> hf; MODE2: P -> f32) ----
// block = 256 thr (4 waves). Tile: M=64 (wave strip 16), N=128, K=128.
// LDS: As[64][136] + Bs[128][136] f16 = 52,224 B.
template<int MODE>
__global__ __launch_bounds__(256) void k_gemm(const void* __restrict__ Asrc,
    const hf* __restrict__ Bt, const float* __restrict__ bias,
    void* __restrict__ Cout){
  constexpr int SA = 136;
  __shared__ alignas(16) hf As[64*SA];
  __shared__ alignas(16) hf Bs[128*SA];
  const int tid = threadIdx.x;
  const int w = tid >> 6, lane = tid & 63;
  const int c = lane & 15, q = lane >> 4;
  const int bx = blockIdx.x;
  const int col0 = (MODE==0) ? blockIdx.y*128 : 0;

  float br[8];
  #pragma unroll
  for (int ni=0; ni<8; ni++) br[ni] = bias[col0 + ni*16 + c];

  f32x4 acc[8];
  #pragma unroll
  for (int ni=0; ni<8; ni++) acc[ni] = (f32x4){0.f,0.f,0.f,0.f};

  // ---- stage A chunk (64 rows x 128 k) ----
  if (MODE == 0){
    const float* A = (const float*)Asrc + (long)bx*64*128;
    #pragma unroll
    for (int v=0; v<8; v++){
      int f4 = v*256 + tid;
      int m = f4 >> 5, k4 = (f4 & 31)*4;
      float4 d = *(const float4*)&A[m*128 + k4];
      hf4 h = {(hf)d.x,(hf)d.y,(hf)d.z,(hf)d.w};
      *(hf4*)&As[m*SA + k4] = h;
    }
  } else {
    const float* A = (const float*)Asrc + (long)(bx>>1)*16384;
    const int i0 = (bx & 1)*64;
    #pragma unroll
    for (int v=0; v<8; v++){
      int f4 = v*256 + tid;
      int t = f4 >> 4, i4 = (f4 & 15)*4;
      float4 d = *(const float4*)&A[t*128 + i0 + i4];
      As[(i4+0)*SA + t] = (hf)d.x;
      As[(i4+1)*SA + t] = (hf)d.y;
      As[(i4+2)*SA + t] = (hf)d.z;
      As[(i4+3)*SA + t] = (hf)d.w;
    }
  }
  // ---- stage B chunk (128 n x 128 k), Bt is f16 [n][128] ----
  #pragma unroll
  for (int v=0; v<8; v++){
    int f8 = v*256 + tid;
    int n = f8 >> 4, k8 = (f8 & 15)*8;
    *(hf8*)&Bs[n*SA + k8] = *(const hf8*)&Bt[(col0+n)*128 + k8];
  }
  __syncthreads();
  // ---- MFMA ----
  #pragma unroll
  for (int kk=0; kk<4; kk++){
    hf8 a = *(const hf8*)&As[(w*16 + c)*SA + kk*32 + q*8];
    #pragma unroll
    for (int ni=0; ni<8; ni++){
      hf8 b = *(const hf8*)&Bs[(ni*16 + c)*SA + kk*32 + q*8];
      acc[ni] = __builtin_amdgcn_mfma_f32_16x16x32_f16(a, b, acc[ni], 0, 0, 0);
    }
  }
  // ---- epilogue ----
  #pragma unroll
  for (int ni=0; ni<8; ni++){
    #pragma unroll
    for (int r=0; r<4; r++){
      int rloc = w*16 + q*4 + r;
      int col = col0 + ni*16 + c;
      float val = acc[ni][r] + br[ni];
      if (MODE == 0){
        int R = bx*64 + rloc;
        int b_ = R >> 7, t_ = R & 127;
        ((hf*)Cout)[(t_*512 + b_)*256 + col] = (hf)val;
      } else {
        int b_ = bx >> 1, i_ = (bx & 1)*64 + rloc;
        ((float*)Cout)[b_*16384 + i_*128 + col] = fast_exp2(C2L*val);
      }
    }
  }
}

// ---------------- recurrence (MFMA, 16 waves, operand-swapped) ----------------
// 32 blocks x 1024 thr (16 waves = 4/SIMD). Block owns batches
// [16*bx,16*bx+16); wave w owns out-cols [16w,16w+16).
// D = Wh^T (A, 32 VGPR/lane) x h^T (B, from LDS). Lane (c,q) gets
// D[oc=16w+4q+r][batch=c]: packed hf4 LDS write + direct hf4 Hb export +
// hf4 xw add (f16 xw). h[16 batches][256] hf in LDS, slot-swizzle
// slot^=(batch&7): B-frag reads and packed writes both 2-way max (free).
// dist-2 xw prefetch; raw lgkm-only barrier (no vmcnt drain), 1/step.
__global__ __launch_bounds__(1024, 4) void k_rnn(const float* __restrict__ h0,
    const float* __restrict__ Wh, const hf* __restrict__ xw,
    hf* __restrict__ Hb){
  __shared__ alignas(16) char hs[2*8192];   // [parity][16 batches x 512B]
  const int tid = threadIdx.x;
  const int w = tid >> 6, lane = tid & 63;
  const int c = lane & 15, q = lane >> 4;
  const int b0 = blockIdx.x * 16;
  const int oc0 = w*16 + 4*q;                // this lane's 4 out-cols
  // ---- Wh as A-frags: aw[kc][e] = Wh[kc*32+q*8+e][w*16+c] ----
  hf8 aw[8];
  #pragma unroll
  for (int kc=0; kc<8; kc++){
    #pragma unroll
    for (int e=0; e<8; e++){
      aw[kc][e] = (hf)Wh[(kc*32 + q*8 + e)*256 + w*16 + c];
    }
  }
  // ---- stage h0 -> hs[parity 0], swizzled [batch][hcol] ----
  if (tid < 512){
    int m = tid >> 5, s8 = tid & 31;         // batch row, 16B slot
    const float* src = &h0[(b0 + m)*256 + s8*8];
    float4 d0 = *(const float4*)&src[0];
    float4 d1 = *(const float4*)&src[4];
    hf8 hv = {(hf)d0.x,(hf)d0.y,(hf)d0.z,(hf)d0.w,
              (hf)d1.x,(hf)d1.y,(hf)d1.z,(hf)d1.w};
    *(hf8*)&hs[m*512 + ((s8 ^ (m & 7)) << 4)] = hv;
  }
  // ---- prologue: xw for t=0 (xA) and t=1 (xB) ----
  float4 xA = ld4h(&xw[(0*512 + b0 + c)*256 + oc0]);
  float4 xB = ld4h(&xw[(1*512 + b0 + c)*256 + oc0]);
  __syncthreads();
  #pragma unroll 1
  for (int t=0; t<128; t+=2){
    #pragma unroll
    for (int half=0; half<2; half++){
      const int T = t + half;
      const int p = T & 1;
      // ---- h B-frags from LDS (swizzled, 2-way free) ----
      hf8 hb[8];
      #pragma unroll
      for (int kc=0; kc<8; kc++)
        hb[kc] = *(const hf8*)&hs[p*8192 + c*512
                                  + ((((kc<<2)|q) ^ (c & 7)) << 4)];
      // ---- 2 independent 4-deep MFMA chains: D = Wh^T x h^T ----
      f32x4 al = (f32x4){0.f,0.f,0.f,0.f}, ah = al;
      #pragma unroll
      for (int kc=0; kc<4; kc++){
        al = __builtin_amdgcn_mfma_f32_16x16x32_f16(aw[kc],   hb[kc],   al,0,0,0);
        ah = __builtin_amdgcn_mfma_f32_16x16x32_f16(aw[kc+4], hb[kc+4], ah,0,0,0);
      }
      // ---- reload xw for T+2 (consumed 2 steps later) ----
      float4 nv = (T+2 < 128)
        ? ld4h(&xw[((T+2)*512 + b0 + c)*256 + oc0])
        : (float4){0.f,0.f,0.f,0.f};
      // ---- tanh (paired rcp) + packed LDS write + direct Hb export ----
      {
        float4 xv = half ? xB : xA;
        float v0 = al[0] + ah[0] + xv.x;
        float v1 = al[1] + ah[1] + xv.y;
        float v2 = al[2] + ah[2] + xv.z;
        float v3 = al[3] + ah[3] + xv.w;
        float ea = fast_exp2(v0*C2L) + 1.f;
        float eb = fast_exp2(v1*C2L) + 1.f;
        float R0 = fast_rcp(ea*eb);
        float ec = fast_exp2(v2*C2L) + 1.f;
        float ed = fast_exp2(v3*C2L) + 1.f;
        float R1 = fast_rcp(ec*ed);
        hf4 h4 = {(hf)fmaf(-2.f*eb, R0, 1.f), (hf)fmaf(-2.f*ea, R0, 1.f),
                  (hf)fmaf(-2.f*ed, R1, 1.f), (hf)fmaf(-2.f*ec, R1, 1.f)};
        *(hf4*)&hs[(p^1)*8192 + c*512
                   + (((oc0 >> 3) ^ (c & 7)) << 4) + (oc0 & 7)*2] = h4;
        *(hf4*)&Hb[(T*512 + b0 + c)*256 + oc0] = h4;
        if (half) xB = nv; else xA = nv;
      }
      // ---- raw barrier: LDS ordering only, no vmcnt drain ----
      asm volatile("s_waitcnt lgkmcnt(0)\n\ts_barrier" ::: "memory");
    }
  }
}

// ---------------- attention (fused Q-gemm) + softmax + scale ----------------
// grid (512 b, 4 t-tiles), 512 threads.
// Prologue: stage Hb tile [32t][264] hf into u0; 8 waves x 2 MFMA tiles
// (M=32,N=128,K=256, 8-deep chains in gemm<256,1>'s k-order -> bit-identical
// Q); exp2(C2L*(S+b2)) written into qs (same u0 region, barrier-separated).
// Main loop: R7 4-way-rcp scalar (proven VALU-roofline form), unchanged.
__global__ __launch_bounds__(512, 4) void k_attn(const float* __restrict__ P,
    const hf* __restrict__ Hbf, const hf* __restrict__ W2t,
    const float* __restrict__ b2, const float* __restrict__ Wv,
    const float* __restrict__ data, float* __restrict__ out){
  __shared__ alignas(16) char u0[32*264*2];         // 16,896B: hstage -> qs
  __shared__ alignas(16) float wvs[128];
  __shared__ alignas(16) float epart[2][4][4][128]; // [parity][quar][tl][i] 16KB
  __shared__ float red[2][4][2];                    // [parity][tl][half]
  hf* hstage = (hf*)u0;                             // [32][264]
  float* qs = (float*)u0;                           // [32][128] after barrier
  const int b = blockIdx.x, tile = blockIdx.y;
  const int tid = threadIdx.x;
  const int i = tid & 127, g = tid >> 7;            // i, tau-quarter 0..3
  const int lane = tid & 63, wvid = tid >> 6;       // for MFMA prologue
  const int c16 = lane & 15, q4 = lane >> 4;
  const int t0 = tile*32;
  // ---- stage Hb tile [32 rows t][256 k] -> hstage[32][264] ----
  #pragma unroll
  for (int v=0; v<2; v++){
    int ch = v*512 + tid;                 // 0..1023
    int row = ch >> 5, k8 = (ch & 31)*8;
    *(hf8*)&hstage[row*264 + k8] =
        *(const hf8*)&Hbf[((long)(t0+row)*512 + b)*256 + k8];
  }
  if (tid < 128) wvs[tid] = -2.f*Wv[tid];
  float4 p4[8];
  const float* prow = P + b*16384 + i*128 + g*32;
  #pragma unroll
  for (int v=0; v<8; v++) p4[v] = *(const float4*)&prow[v*4];
  __syncthreads();
  // ---- MFMA: wave wvid -> m-block (wvid&1)*16, col-blocks (wvid>>1)*32+{0,16}
  f32x4 sacc[2];
  #pragma unroll
  for (int hh=0; hh<2; hh++){
    const int n0 = (wvid>>1)*32 + hh*16;
    f32x4 accq = (f32x4){0.f,0.f,0.f,0.f};
    #pragma unroll
    for (int kc=0; kc<8; kc++){
      hf8 a = *(const hf8*)&hstage[((wvid&1)*16 + c16)*264 + kc*32 + q4*8];
      hf8 bf = *(const hf8*)&W2t[(n0 + c16)*256 + kc*32 + q4*8];
      accq = __builtin_amdgcn_mfma_f32_16x16x32_f16(a, bf, accq, 0,0,0);
    }
    sacc[hh] = accq;
  }
  float bb0 = b2[(wvid>>1)*32 + c16];
  float bb1 = b2[(wvid>>1)*32 + 16 + c16];
  __syncthreads();            // all hstage reads done; u0 becomes qs
  #pragma unroll
  for (int hh=0; hh<2; hh++){
    const int n0 = (wvid>>1)*32 + hh*16;
    const float bb = hh ? bb1 : bb0;
    #pragma unroll
    for (int r=0; r<4; r++){
      int row = (wvid&1)*16 + q4*4 + r;
      qs[row*128 + n0 + c16] = fast_exp2(C2L*(sacc[hh][r] + bb));
    }
  }
  __syncthreads();
  // ---- main loop (unchanged) ----
  for (int tp=0; tp<8; tp++){
    const int pp = tp & 1;
    const float* qb  = &qs[(4*tp)*128 + g*32];
    const float* wvr = &wvs[g*32];
    float acc0=0.f, acc1=0.f, acc2=0.f, acc3=0.f;
    #pragma unroll
    for (int mm=0; mm<8; mm++){
      float4 Pv = p4[mm];
      float4 wv = *(const float4*)&wvr[mm*4];
      #pragma unroll
      for (int tl=0; tl<4; tl++){
        float4 qq = *(const float4*)&qb[tl*128 + mm*4];
        float u = fmaf(Pv.x, qq.x, 1.f), v = fmaf(Pv.y, qq.y, 1.f);
        float x = fmaf(Pv.z, qq.z, 1.f), y = fmaf(Pv.w, qq.w, 1.f);
        float d01 = u*v, d23 = x*y;
        float n01 = fmaf(wv.x, v, wv.y*u);
        float n23 = fmaf(wv.z, y, wv.w*x);
        float N = fmaf(n01, d23, n23*d01);
        float r = fast_rcp(d01*d23);
        float term = N*r;
        if (tl==0) acc0 += term;
        else if (tl==1) acc1 += term;
        else if (tl==2) acc2 += term;
        else acc3 += term;
      }
    }
    epart[pp][g][0][i] = acc0;
    epart[pp][g][1][i] = acc1;
    epart[pp][g][2][i] = acc2;
    epart[pp][g][3][i] = acc3;
    __syncthreads();
    // thread handles tl = g for the reduction + output
    float e = epart[pp][0][g][i] + epart[pp][1][g][i]
            + epart[pp][2][g][i] + epart[pp][3][g][i];
    float pe = fast_exp2(e*L2E);
    float sm = pe;
    #pragma unroll
    for (int off=32; off; off>>=1) sm += __shfl_xor(sm, off);
    if ((tid & 63) == 0) red[pp][g][(tid>>6)&1] = sm;
    __syncthreads();
    float ssum = red[pp][g][0] + red[pp][g][1];
    float alpha = pe * fast_rcp(ssum);
    int t = t0 + 4*tp + g;
    int base = (t*512 + b)*128 + i;
    out[base] = data[base]*alpha;
  }
}

extern "C" void kernel_launch(void* const* d_in, const int* in_sizes, int n_in,
                              void* d_out, int out_size, void* d_ws, size_t ws_size,
                              hipStream_t stream) {
  const float* data = (const float*)d_in[0];
  const float* h0   = (const float*)d_in[1];
  const float* Wx   = (const float*)d_in[2];
  const float* Wh   = (const float*)d_in[3];
  const float* bb   = (const float*)d_in[4];
  const float* W1   = (const float*)d_in[5];
  const float* b1   = (const float*)d_in[6];
  const float* W2   = (const float*)d_in[7];
  const float* b2   = (const float*)d_in[8];
  const float* Wv   = (const float*)d_in[9];
  // d_in[10] = bv: softmax-invariant constant, dropped. d_in[11] = n (128).
  float* wsp = (float*)d_ws;
  float* P   = wsp;                         //  8,388,608 f
  hf*    xwh = (hf*)(wsp + 8388608);        // xw in f16 [t][b][256]
  hf*    Hbf = (hf*)(wsp + 25165824);       // 16,777,216 hf [t][b][256]
  hf*    wts = (hf*)(wsp + 33554432);       // 81,920 hf
  const hf* Wxt = wts;                      // [256][128]
  const hf* W2t = wts + 32768;              // [128][256]
  const hf* W1t = wts + 65536;              // [128][128]
  float* out = (float*)d_out;

  hipLaunchKernelGGL(k_prep_w, dim3(320), dim3(256), 0, stream, Wx, W2, W1, wts);
  hipLaunchKernelGGL((k_gemm<0>), dim3(1024,2), dim3(256), 0, stream,
                     (const void*)data, Wxt, bb, (void*)xwh);
  hipLaunchKernelGGL((k_gemm<2>), dim3(1024),   dim3(256), 0, stream,
                     (const void*)data, W1t, b1, (void*)P);
  hipLaunchKernelGGL(k_rnn, dim3(32), dim3(1024), 0, stream, h0, Wh, xwh, Hbf);
  hipLaunchKernelGGL(k_attn, dim3(512, 4), dim3(512), 0, stream,
                     P, Hbf, W2t, b2, Wv, data, out);
}